// Round 19
// baseline (313.953 us; speedup 1.0000x reference)
//
#include <hip/hip_runtime.h>
#include <hip/hip_fp16.h>
#include <math.h>

// Problem dims
#define Bb 256
#define Nn 196
#define Dd 512
#define Hh 102
#define Kk 64
#define Mm 40

// ws layout (bytes):
//   [0, 25690112)          (unused; former logits)
//   [W1H_OFF, +262144)     w1g_hi [2][128][512] bf16 (g-folded, transposed, j-padded)
//   [W1L_OFF, +262144)     w1g_lo
//   [GWB1_OFF, +2048)      gwb1 [2][128][2] f32 (Gw, B1)
//   [W2TH_OFF, +32768)     w2t_hi [2][64 k][128 j] bf16 (transposed, j-padded)
//   [W2TL_OFF, +32768)     w2t_lo
//   [H_OFF, +29360128)     h_hi [1024 blk][112][128] bf16 (gelu'd hidden)
//   [HL_OFF, +29360128)    h_lo
//   [AGG_OFF, +33554432)   aggP [2][B][64][512] fp16    total ~118.6 MB
#define W1H_OFF  ((size_t)25690112)
#define W1L_OFF  (W1H_OFF + 262144)
#define GWB1_OFF (W1L_OFF + 262144)
#define W2TH_OFF (GWB1_OFF + 2048)
#define W2TL_OFF (W2TH_OFF + 32768)
#define H_OFF    (W2TL_OFF + 32768)
#define HL_OFF   (H_OFF + 29360128)
#define AGG_OFF  (HL_OFF + 29360128)

using short8 = __attribute__((ext_vector_type(8))) short;
using f32x4  = __attribute__((ext_vector_type(4))) float;

// T4 barrier: drain LDS queue (writer-side visibility) but leave global
// loads IN FLIGHT across the barrier — no vmcnt(0) drain.
__device__ __forceinline__ void barrier_lgkm_only() {
  asm volatile("s_waitcnt lgkmcnt(0)" ::: "memory");
  __builtin_amdgcn_s_barrier();
  asm volatile("" ::: "memory");
}

__device__ __forceinline__ float dot4(const float4 a, const float4 b) {
  return a.x*b.x + a.y*b.y + a.z*b.z + a.w*b.w;
}
__device__ __forceinline__ float4 ld4s(const float* p) { return *(const float4*)p; }
__device__ __forceinline__ float gelu1(float z) {
  return 0.5f * z * (1.f + erff(z * 0.70710678118f));
}
__device__ __forceinline__ unsigned short bf16hi(float v) {
  return (unsigned short)(__float_as_uint(v) >> 16);
}
__device__ __forceinline__ float hipart(float v) {
  return __uint_as_float(__float_as_uint(v) & 0xffff0000u);
}
__device__ __forceinline__ unsigned short f2h(float v) {
  __half h = __float2half(v);
  return *(unsigned short*)&h;
}
__device__ __forceinline__ float h2f(unsigned short u) {
  __half h = *(__half*)&u;
  return __half2float(h);
}
__device__ __forceinline__ void split8(const float4 va, const float4 vb,
                                       short8& hh, short8& ll) {
  hh[0] = (short)bf16hi(va.x); ll[0] = (short)bf16hi(va.x - hipart(va.x));
  hh[1] = (short)bf16hi(va.y); ll[1] = (short)bf16hi(va.y - hipart(va.y));
  hh[2] = (short)bf16hi(va.z); ll[2] = (short)bf16hi(va.z - hipart(va.z));
  hh[3] = (short)bf16hi(va.w); ll[3] = (short)bf16hi(va.w - hipart(va.w));
  hh[4] = (short)bf16hi(vb.x); ll[4] = (short)bf16hi(vb.x - hipart(vb.x));
  hh[5] = (short)bf16hi(vb.y); ll[5] = (short)bf16hi(vb.y - hipart(vb.y));
  hh[6] = (short)bf16hi(vb.z); ll[6] = (short)bf16hi(vb.z - hipart(vb.z));
  hh[7] = (short)bf16hi(vb.w); ll[7] = (short)bf16hi(vb.w - hipart(vb.w));
}
__device__ __forceinline__ float wave_reduce_sum(float v) {
#pragma unroll
  for (int o = 1; o < 64; o <<= 1) v += __shfl_xor(v, o, 64);
  return v;
}
__device__ __forceinline__ float wave_reduce_max(float v) {
#pragma unroll
  for (int o = 1; o < 64; o <<= 1) v = fmaxf(v, __shfl_xor(v, o, 64));
  return v;
}

// ---------------------------------------------------------------------------
// K0w: grid (2 paths, 9 slices). Slices 0-7: w1g = g(.)w1 transposed, split
// bf16 hi/lo. Slice 0 also Gw/B1. Slice 8: w2 transposed [64 k][128 j] split.
// ---------------------------------------------------------------------------
__global__ __launch_bounds__(512) void k0_wprep(
    const float* __restrict__ g_s, const float* __restrict__ b_s,
    const float* __restrict__ w1_s, const float* __restrict__ b1_s,
    const float* __restrict__ w2_s,
    const float* __restrict__ g_d, const float* __restrict__ b_d,
    const float* __restrict__ w1_d, const float* __restrict__ b1_d,
    const float* __restrict__ w2_d,
    unsigned short* __restrict__ w1h, unsigned short* __restrict__ w1l,
    float* __restrict__ gwb1,
    unsigned short* __restrict__ w2th, unsigned short* __restrict__ w2tl)
{
  const int p = blockIdx.x, slice = blockIdx.y;
  const float* g  = p ? g_d  : g_s;
  const float* bb = p ? b_d  : b_s;
  const float* w1 = p ? w1_d : w1_s;
  const float* b1 = p ? b1_d : b1_s;
  const float* w2 = p ? w2_d : w2_s;
  const int tid = threadIdx.x;

  if (slice < 8) {
    for (int idx = slice * 8192 + tid; idx < slice * 8192 + 8192; idx += 512) {
      const int j = idx & 127, c = idx >> 7;
      const float v = (j < Hh) ? w1[(size_t)c * Hh + j] * g[c] : 0.f;
      w1h[((size_t)(p * 128 + j)) * 512 + c] = bf16hi(v);
      w1l[((size_t)(p * 128 + j)) * 512 + c] = bf16hi(v - hipart(v));
    }
  } else {
    for (int idx = tid; idx < 8192; idx += 512) {
      const int k = idx >> 7, j = idx & 127;
      const float v = (j < Hh) ? w2[(size_t)j * Kk + k] : 0.f;
      w2th[(size_t)(p * 64 + k) * 128 + j] = bf16hi(v);
      w2tl[(size_t)(p * 64 + k) * 128 + j] = bf16hi(v - hipart(v));
    }
  }

  if (slice == 0) {
    __shared__ float red[4][128][2];
    const int j = tid & 127, part = tid >> 7;
    float sg = 0.f, sb = 0.f;
    if (j < Hh) {
      for (int c = part * 128; c < part * 128 + 128; ++c) {
        const float w = w1[(size_t)c * Hh + j];
        sg += g[c] * w;
        sb += bb[c] * w;
      }
    }
    red[part][j][0] = sg;
    red[part][j][1] = sb;
    __syncthreads();
    if (part == 0) {
      const float G  = red[0][j][0] + red[1][j][0] + red[2][j][0] + red[3][j][0];
      const float Bv = red[0][j][1] + red[1][j][1] + red[2][j][1] + red[3][j][1];
      gwb1[(p * 128 + j) * 2]     = G;
      gwb1[(p * 128 + j) * 2 + 1] = (j < Hh) ? (Bv + b1[j]) : 0.f;
    }
  }
}

// ---------------------------------------------------------------------------
// K1a: h-GEMM only. Double-buffered split-bf16 MFMA K-loop, T4 barriers,
// depth-2 x prefetch. LN folded into epilogue; h written split-bf16 to ws.
// ---------------------------------------------------------------------------
__global__ __launch_bounds__(512) void k1a_hgemm(
    const float* __restrict__ x_s, const float* __restrict__ x_d,
    const unsigned short* __restrict__ w1h, const unsigned short* __restrict__ w1l,
    const float* __restrict__ gwb1,
    unsigned short* __restrict__ h_hi, unsigned short* __restrict__ h_lo)
{
  __shared__ __align__(16) char smem1[40320];
  unsigned short* xbuf = (unsigned short*)smem1;
  float* part = (float*)(smem1 + 35840);
  float* st   = (float*)(smem1 + 39424);

  const int tid = threadIdx.x;
  const int ntile = blockIdx.x, p = blockIdx.y, b = blockIdx.z;
  const int nbase = ntile * 112;
  const float* x  = p ? x_d : x_s;

  const int lane = tid & 63, wv = tid >> 6;
  const int lr = lane & 15, lg = lane >> 4;
  const int jb = wv * 16;
  const unsigned short* wph = w1h + ((size_t)(p * 128 + jb + lr)) * 512 + lg * 8;
  const unsigned short* wpl = w1l + ((size_t)(p * 128 + jb + lr)) * 512 + lg * 8;

  const int t = tid >> 2, q = tid & 3;
  const bool stg = (tid < 448);
  const int n = nbase + t;
  const bool valid = stg && (n < Nn);
  const float* xrow = x + ((size_t)(b * Nn + (valid ? n : 0))) * Dd + q * 8;

  float psum = 0.f, psq = 0.f;
  f32x4 acc0 = {0,0,0,0}, acc1 = acc0, acc2 = acc0, acc3 = acc0;
  f32x4 acc4 = acc0, acc5 = acc0, acc6 = acc0;

  short8 bh_c = *(const short8*)(wph);
  short8 bl_c = *(const short8*)(wpl);

  {
    float4 va = {0,0,0,0}, vb = va;
    if (valid) { va = ld4s(xrow); vb = ld4s(xrow + 4); }
    if (stg) {
      psum += va.x + va.y + va.z + va.w + vb.x + vb.y + vb.z + vb.w;
      psq  += dot4(va, va) + dot4(vb, vb);
      short8 hh, ll;
      split8(va, vb, hh, ll);
      *(short8*)(xbuf + t * 40 + q * 8) = hh;
      *(short8*)(xbuf + 4480 + t * 40 + q * 8) = ll;
    }
  }
  float4 pva = {0,0,0,0}, pvb = pva;
  if (valid) { pva = ld4s(xrow + 32); pvb = ld4s(xrow + 36); }
  barrier_lgkm_only();

#pragma unroll 1
  for (int ch = 0; ch < 16; ++ch) {
    const int buf = ch & 1;
    const unsigned short* xh = xbuf + buf * 8960;
    const unsigned short* xl = xh + 4480;

    float4 nva = {0,0,0,0}, nvb = nva;
    if (ch < 14 && valid) {
      const int co = (ch + 2) * 32;
      nva = ld4s(xrow + co);
      nvb = ld4s(xrow + co + 4);
    }
    short8 bh_n = bh_c, bl_n = bl_c;
    if (ch < 15) {
      const int co = (ch + 1) * 32;
      bh_n = *(const short8*)(wph + co);
      bl_n = *(const short8*)(wpl + co);
    }

#define MSTEP(A, M) { \
    const short8 ah = *(const short8*)(xh + ((M) * 16 + lr) * 40 + lg * 8); \
    const short8 al = *(const short8*)(xl + ((M) * 16 + lr) * 40 + lg * 8); \
    (A) = __builtin_amdgcn_mfma_f32_16x16x32_bf16(ah, bh_c, (A), 0, 0, 0); \
    (A) = __builtin_amdgcn_mfma_f32_16x16x32_bf16(ah, bl_c, (A), 0, 0, 0); \
    (A) = __builtin_amdgcn_mfma_f32_16x16x32_bf16(al, bh_c, (A), 0, 0, 0); }
    MSTEP(acc0, 0) MSTEP(acc1, 1) MSTEP(acc2, 2) MSTEP(acc3, 3)
    MSTEP(acc4, 4) MSTEP(acc5, 5) MSTEP(acc6, 6)
#undef MSTEP

    if (ch < 15 && stg) {
      psum += pva.x + pva.y + pva.z + pva.w + pvb.x + pvb.y + pvb.z + pvb.w;
      psq  += dot4(pva, pva) + dot4(pvb, pvb);
      short8 hh, ll;
      split8(pva, pvb, hh, ll);
      unsigned short* xw = xbuf + (buf ^ 1) * 8960;
      *(short8*)(xw + t * 40 + q * 8) = hh;
      *(short8*)(xw + 4480 + t * 40 + q * 8) = ll;
    }
    pva = nva; pvb = nvb;
    bh_c = bh_n; bl_c = bl_n;
    barrier_lgkm_only();
  }

  // LN stats
  if (stg) {
    part[t * 8 + q * 2]     = psum;
    part[t * 8 + q * 2 + 1] = psq;
  }
  __syncthreads();
  if (tid < 112) {
    const float s  = part[tid * 8] + part[tid * 8 + 2] + part[tid * 8 + 4] + part[tid * 8 + 6];
    const float ss = part[tid * 8 + 1] + part[tid * 8 + 3] + part[tid * 8 + 5] + part[tid * 8 + 7];
    const float mu  = s * (1.f / 512.f);
    const float var = fmaxf(ss * (1.f / 512.f) - mu * mu, 0.f);
    st[2 * tid]     = mu;
    st[2 * tid + 1] = rsqrtf(var + 1e-5f);
  }
  __syncthreads();

  // epilogue: h = gelu(rs*S - mu*rs*Gw + B1) -> global split-bf16
  const int colw = jb + lr;
  const float Gw = gwb1[(p * 128 + colw) * 2];
  const float B1 = gwb1[(p * 128 + colw) * 2 + 1];
  const size_t hoff = (size_t)((b * 2 + p) * 2 + ntile) * 14336 + colw;
#define HW1(A, M) { \
    _Pragma("unroll") \
    for (int rr = 0; rr < 4; ++rr) { \
      const int row = (M) * 16 + lg * 4 + rr; \
      const float mu = st[2 * row], rs = st[2 * row + 1]; \
      const float hv = gelu1(rs * (A)[rr] - mu * rs * Gw + B1); \
      h_hi[hoff + row * 128] = bf16hi(hv); \
      h_lo[hoff + row * 128] = bf16hi(hv - hipart(hv)); \
    } }
  HW1(acc0, 0) HW1(acc1, 1) HW1(acc2, 2) HW1(acc3, 3)
  HW1(acc4, 4) HW1(acc5, 5) HW1(acc6, 6)
#undef HW1
}

// ---------------------------------------------------------------------------
// K2 v5: ONE block per (p, b). Phase A: logits[64][224] = w2t @ h^T + b2 via
// split-bf16 MFMA into LDS [64][233] f32 (stride 233: bank-spread). Softmax
// max/sum from LDS; A-frags (unnormalized e) built ON THE FLY into registers
// (exp at build). lgL region then recycled as xT double-buffer; chunk loop
// identical to v4. aggP out as fp16; 1/sum folded at store.
// ---------------------------------------------------------------------------
__global__ __launch_bounds__(512) void k2_softmax_agg(
    const float* __restrict__ x_s, const float* __restrict__ x_d,
    const unsigned short* __restrict__ h_hi, const unsigned short* __restrict__ h_lo,
    const unsigned short* __restrict__ w2th, const unsigned short* __restrict__ w2tl,
    const float* __restrict__ b2_s, const float* __restrict__ b2_d,
    const float* __restrict__ scale, unsigned short* __restrict__ aggP)
{
  // [0,65536) union { lgL [64][233] f32 (59648 B) | xT bufs 2 x 32768 }
  // [65536,65792) rsk[64] ; [65792,67968) redf[8][68] ; [67968,68224) mxk[64]
  __shared__ __align__(16) unsigned char smem2[68224];
  float* lgL  = (float*)smem2;
  float* rsk  = (float*)(smem2 + 65536);
  float* redf = (float*)(smem2 + 65792);
  float* mxk  = (float*)(smem2 + 67968);

  const int tid = threadIdx.x;
  const int p = blockIdx.x, b = blockIdx.y;
  const float sc = scale[0];
  const float* xb = (p ? x_d : x_s) + (size_t)b * Nn * Dd;
  const float* b2 = p ? b2_d : b2_s;

  const int lane = tid & 63, wv = tid >> 6;
  const int lr = lane & 15, lg = lane >> 4;

  // ---- phase A: logits -> lgL ----
  {
    const int kt = wv & 3;
    const unsigned short* awh = w2th + (size_t)p * 8192 + (kt * 16 + lr) * 128 + lg * 8;
    const unsigned short* awl = w2tl + (size_t)p * 8192 + (kt * 16 + lr) * 128 + lg * 8;
#pragma unroll 1
    for (int i = 0; i < 7; ++i) {
      const int nt = (wv >> 2) * 7 + i;
      const int n = nt * 16 + lr;
      const int tile = (n >= 112) ? 1 : 0;
      const size_t hb = ((size_t)((b * 2 + p) * 2 + tile)) * 14336
                      + (size_t)(n - tile * 112) * 128 + lg * 8;
      f32x4 acc = {0.f, 0.f, 0.f, 0.f};
#pragma unroll
      for (int j0 = 0; j0 < 128; j0 += 32) {
        const short8 Awh = *(const short8*)(awh + j0);
        const short8 Awl = *(const short8*)(awl + j0);
        const short8 Bh  = *(const short8*)(h_hi + hb + j0);
        const short8 Bl  = *(const short8*)(h_lo + hb + j0);
        acc = __builtin_amdgcn_mfma_f32_16x16x32_bf16(Awh, Bh, acc, 0, 0, 0);
        acc = __builtin_amdgcn_mfma_f32_16x16x32_bf16(Awh, Bl, acc, 0, 0, 0);
        acc = __builtin_amdgcn_mfma_f32_16x16x32_bf16(Awl, Bh, acc, 0, 0, 0);
      }
#pragma unroll
      for (int rr = 0; rr < 4; ++rr) {
        const int k = kt * 16 + lg * 4 + rr;
        lgL[k * 233 + nt * 16 + lr] = acc[rr] + b2[k];
      }
    }
  }
  __syncthreads();

  // ---- softmax reductions from lgL ----
  const int kloc = tid & 63, sprt = tid >> 6;
  float mx = -1e30f;
  for (int nn = sprt; nn < Nn; nn += 8) mx = fmaxf(mx, lgL[kloc * 233 + nn] * sc);
  redf[sprt * 68 + kloc] = mx;
  __syncthreads();
  if (tid < 64) {
    float m = redf[tid];
#pragma unroll
    for (int gg = 1; gg < 8; ++gg) m = fmaxf(m, redf[gg * 68 + tid]);
    mxk[tid] = m;
  }
  __syncthreads();
  const float mk = mxk[kloc];
  float ssum = 0.f;
  for (int nn = sprt; nn < Nn; nn += 8) ssum += expf(lgL[kloc * 233 + nn] * sc - mk);
  redf[sprt * 68 + kloc] = ssum;
  __syncthreads();
  if (tid < 64) {
    float s = 0.f;
#pragma unroll
    for (int gg = 0; gg < 8; ++gg) s += redf[gg * 68 + tid];
    rsk[tid] = 1.f / s;
  }
  __syncthreads();

  // ---- A-frags (unnormalized e) built on the fly into registers ----
  const int kt = wv & 3, ct = wv >> 2;
  const int arow = kt * 16 + lr;
  const float mka = mxk[arow];
  short8 Ah0, Ah1, Ah2, Ah3, Ah4, Ah5, Ah6;
  short8 Al0, Al1, Al2, Al3, Al4, Al5, Al6;
#define BUILD(I) { short8 h8, l8; \
  _Pragma("unroll") \
  for (int e = 0; e < 8; ++e) { \
    const int nA = (I) * 32 + lg * 8 + e; \
    const float v = (nA < Nn) ? expf(lgL[arow * 233 + nA] * sc - mka) : 0.f; \
    h8[e] = (short)bf16hi(v); l8[e] = (short)bf16hi(v - hipart(v)); } \
  Ah##I = h8; Al##I = l8; }
  BUILD(0) BUILD(1) BUILD(2) BUILD(3) BUILD(4) BUILD(5) BUILD(6)
#undef BUILD
  const int kbase = kt * 16 + lg * 4;
  const float r0 = rsk[kbase], r1 = rsk[kbase + 1];
  const float r2 = rsk[kbase + 2], r3 = rsk[kbase + 3];
  barrier_lgkm_only();   // all lgL reads done before region reused for xT

  // ---- chunk loop: double-buffered swizzled xT staging, b64 writes ----
  const int brow = ct * 16 + lr;
  const int bswz = (brow & 31) << 3;
  const size_t agk = (size_t)((p * Bb + b) * Kk + kbase) * Dd;

#define K2STAGE(CHN, BUF) { \
    const int c0s = (CHN) * 32; \
    unsigned short* th = (unsigned short*)(smem2 + (BUF) * 32768); \
    unsigned short* tl = (unsigned short*)(smem2 + (BUF) * 32768 + 16384); \
    _Pragma("unroll") \
    for (int it = 0; it < 4; ++it) { \
      const int idx = it * 512 + tid; \
      const int cl = idx & 31, ngr = idx >> 5; \
      if (ngr < 56) { \
        const int n0 = ngr * 4; \
        const float* xpp = xb + (size_t)n0 * Dd + c0s + cl; \
        const float v0 = (n0     < Nn) ? xpp[0]      : 0.f; \
        const float v1 = (n0 + 1 < Nn) ? xpp[Dd]     : 0.f; \
        const float v2 = (n0 + 2 < Nn) ? xpp[2 * Dd] : 0.f; \
        const float v3 = (n0 + 3 < Nn) ? xpp[3 * Dd] : 0.f; \
        ushort4 hh4, ll4; \
        hh4.x = bf16hi(v0); ll4.x = bf16hi(v0 - hipart(v0)); \
        hh4.y = bf16hi(v1); ll4.y = bf16hi(v1 - hipart(v1)); \
        hh4.z = bf16hi(v2); ll4.z = bf16hi(v2 - hipart(v2)); \
        hh4.w = bf16hi(v3); ll4.w = bf16hi(v3 - hipart(v3)); \
        const int ph = cl * 256 + (n0 ^ ((cl & 31) << 3)); \
        *(ushort4*)(th + ph) = hh4; \
        *(ushort4*)(tl + ph) = ll4; \
      } \
    } }

  K2STAGE(0, 0)
  barrier_lgkm_only();

#pragma unroll 1
  for (int chn = 0; chn < 16; ++chn) {
    const int buf = chn & 1;
    if (chn < 15) { K2STAGE(chn + 1, buf ^ 1) }

    const unsigned short* bhb = (const unsigned short*)(smem2 + buf * 32768) + brow * 256;
    const unsigned short* blb = (const unsigned short*)(smem2 + buf * 32768 + 16384) + brow * 256;
    f32x4 acc = {0.f, 0.f, 0.f, 0.f};
#define K2KS(I) { \
    const int off = ((I) * 32 + lg * 8) ^ bswz; \
    const short8 Bh = *(const short8*)(bhb + off); \
    const short8 Bl = *(const short8*)(blb + off); \
    acc = __builtin_amdgcn_mfma_f32_16x16x32_bf16(Ah##I, Bh, acc, 0, 0, 0); \
    acc = __builtin_amdgcn_mfma_f32_16x16x32_bf16(Ah##I, Bl, acc, 0, 0, 0); \
    acc = __builtin_amdgcn_mfma_f32_16x16x32_bf16(Al##I, Bh, acc, 0, 0, 0); }
    K2KS(0) K2KS(1) K2KS(2) K2KS(3) K2KS(4) K2KS(5) K2KS(6)
#undef K2KS

    const int cc = chn * 32 + ct * 16 + lr;
    aggP[agk              + cc] = f2h(acc[0] * r0);
    aggP[agk +     (size_t)Dd + cc] = f2h(acc[1] * r1);
    aggP[agk + 2 * (size_t)Dd + cc] = f2h(acc[2] * r2);
    aggP[agk + 3 * (size_t)Dd + cc] = f2h(acc[3] * r3);
    barrier_lgkm_only();
  }
#undef K2STAGE
}

// ---------------------------------------------------------------------------
// K4: per b, 512 threads: lane owns k; swizzled vt LDS; register dots.
// aggP is fp16 (converted to f32 at staging).
// ---------------------------------------------------------------------------
__global__ __launch_bounds__(512) void k4_final(
    const float* __restrict__ words, const unsigned short* __restrict__ aggP,
    float* __restrict__ outp)
{
  __shared__ __align__(16) unsigned char vls[64 * 512];
  __shared__ float rowm[40];
  __shared__ float colp[8][72];
  const int tid = threadIdx.x, b = blockIdx.x;
  const int w = tid >> 6, lane = tid & 63;
  const unsigned short* a0 = aggP + (size_t)b * (Kk * Dd);
  const unsigned short* a1 = aggP + ((size_t)(Bb + b)) * (Kk * Dd);
  const float* wrd = words + (size_t)b * Mm * Dd;
  const int m0 = w * 5;

  float rnt0, rnt1, rnt2, rnt3, rnt4;
#define TNORM(R, I) { \
    const float* tr = wrd + (size_t)(m0 + (I)) * Dd + lane * 8; \
    float4 ta = ld4s(tr), tb = ld4s(tr + 4); \
    float ss = wave_reduce_sum(dot4(ta, ta) + dot4(tb, tb)); \
    R = 1.f / fmaxf(sqrtf(ss), 1e-8f); }
  TNORM(rnt0, 0) TNORM(rnt1, 1) TNORM(rnt2, 2) TNORM(rnt3, 3) TNORM(rnt4, 4)
#undef TNORM

  float acc0 = 0.f, acc1 = 0.f, acc2 = 0.f, acc3 = 0.f, acc4 = 0.f, vsq = 0.f;

#pragma unroll 1
  for (int chn = 0; chn < 4; ++chn) {
    const int c0 = chn * 128;
    __syncthreads();
#pragma unroll
    for (int s = 0; s < 2; ++s) {
      const int idx = tid + s * 512;
      const int k = idx >> 4, g2 = idx & 15;
      const unsigned short* ph0 = a0 + (size_t)k * Dd + c0 + g2 * 8;
      const unsigned short* ph1 = a1 + (size_t)k * Dd + c0 + g2 * 8;
      const ushort4 u0a = *(const ushort4*)(ph0);
      const ushort4 u0b = *(const ushort4*)(ph0 + 4);
      const ushort4 u1a = *(const ushort4*)(ph1);
      const ushort4 u1b = *(const ushort4*)(ph1 + 4);
      float4 sa = {h2f(u0a.x) + h2f(u1a.x), h2f(u0a.y) + h2f(u1a.y),
                   h2f(u0a.z) + h2f(u1a.z), h2f(u0a.w) + h2f(u1a.w)};
      float4 sb = {h2f(u0b.x) + h2f(u1b.x), h2f(u0b.y) + h2f(u1b.y),
                   h2f(u0b.z) + h2f(u1b.z), h2f(u0b.w) + h2f(u1b.w)};
      const int gc0 = g2 * 2, gc1 = gc0 + 1;
      *(float4*)(vls + k * 512 + ((gc0 ^ (k & 31)) << 4)) = sa;
      *(float4*)(vls + k * 512 + ((gc1 ^ (k & 31)) << 4)) = sb;
    }
    __syncthreads();
#pragma unroll 2
    for (int cc = 0; cc < 32; ++cc) {
      const float4 vv = *(const float4*)(vls + lane * 512 + ((cc ^ (lane & 31)) << 4));
      const float* tp = wrd + c0 + cc * 4;
      const float4 t0 = ld4s(tp + (size_t)(m0    ) * Dd);
      const float4 t1 = ld4s(tp + (size_t)(m0 + 1) * Dd);
      const float4 t2 = ld4s(tp + (size_t)(m0 + 2) * Dd);
      const float4 t3 = ld4s(tp + (size_t)(m0 + 3) * Dd);
      const float4 t4 = ld4s(tp + (size_t)(m0 + 4) * Dd);
      acc0 += dot4(t0, vv); acc1 += dot4(t1, vv); acc2 += dot4(t2, vv);
      acc3 += dot4(t3, vv); acc4 += dot4(t4, vv);
      vsq  += dot4(vv, vv);
    }
  }

  const float rnv = 1.f / fmaxf(sqrtf(vsq), 1e-8f);
  float cmax = -1e30f;
#define DOM(ACC, RNT, I) { \
    float s = (ACC) * (RNT) * rnv; \
    s = (s >= 0.f) ? s : 0.1f * s; \
    cmax = fmaxf(cmax, s); \
    float rm = wave_reduce_max(s); \
    if (lane == 0) rowm[m0 + (I)] = rm; }
  DOM(acc0, rnt0, 0) DOM(acc1, rnt1, 1) DOM(acc2, rnt2, 2)
  DOM(acc3, rnt3, 3) DOM(acc4, rnt4, 4)
#undef DOM
  colp[w][lane] = cmax;
  __syncthreads();
  if (w == 0) {
    float cm = colp[0][lane];
#pragma unroll
    for (int ww = 1; ww < 8; ++ww) cm = fmaxf(cm, colp[ww][lane]);
    const float csum = wave_reduce_sum(cm);
    const float rv = (lane < 40) ? rowm[lane] : 0.f;
    const float rsum = wave_reduce_sum(rv);
    if (lane == 0) outp[b] = rsum * (1.f / 40.f) + csum * (1.f / 64.f);
  }
}

extern "C" void kernel_launch(void* const* d_in, const int* in_sizes, int n_in,
                              void* d_out, int out_size, void* d_ws, size_t ws_size,
                              hipStream_t stream)
{
  const float* x_s   = (const float*)d_in[0];
  const float* x_d   = (const float*)d_in[1];
  const float* words = (const float*)d_in[2];
  const float* g_s   = (const float*)d_in[3];
  const float* b_s   = (const float*)d_in[4];
  const float* w1_s  = (const float*)d_in[5];
  const float* b1_s  = (const float*)d_in[6];
  const float* w2_s  = (const float*)d_in[7];
  const float* b2_s  = (const float*)d_in[8];
  const float* g_d   = (const float*)d_in[9];
  const float* b_d   = (const float*)d_in[10];
  const float* w1_d  = (const float*)d_in[11];
  const float* b1_d  = (const float*)d_in[12];
  const float* w2_d  = (const float*)d_in[13];
  const float* b2_d  = (const float*)d_in[14];
  const float* scale = (const float*)d_in[15];
  (void)in_sizes; (void)n_in; (void)out_size; (void)ws_size;

  char* ws = (char*)d_ws;
  unsigned short* w1h  = (unsigned short*)(ws + W1H_OFF);
  unsigned short* w1l  = (unsigned short*)(ws + W1L_OFF);
  float* gwb1          = (float*)(ws + GWB1_OFF);
  unsigned short* w2th = (unsigned short*)(ws + W2TH_OFF);
  unsigned short* w2tl = (unsigned short*)(ws + W2TL_OFF);
  unsigned short* h_hi = (unsigned short*)(ws + H_OFF);
  unsigned short* h_lo = (unsigned short*)(ws + HL_OFF);
  unsigned short* aggP = (unsigned short*)(ws + AGG_OFF);

  hipLaunchKernelGGL(k0_wprep, dim3(2, 9), dim3(512), 0, stream,
                     g_s, b_s, w1_s, b1_s, w2_s, g_d, b_d, w1_d, b1_d, w2_d,
                     w1h, w1l, gwb1, w2th, w2tl);
  hipLaunchKernelGGL(k1a_hgemm, dim3(2, 2, 256), dim3(512), 0, stream,
                     x_s, x_d, w1h, w1l, gwb1, h_hi, h_lo);
  hipLaunchKernelGGL(k2_softmax_agg, dim3(2, Bb), dim3(512), 0, stream,
                     x_s, x_d, h_hi, h_lo, w2th, w2tl, b2_s, b2_d, scale, aggP);
  hipLaunchKernelGGL(k4_final, dim3(256), dim3(512), 0, stream,
                     words, aggP, (float*)d_out);
}

// Round 20
// 268.346 us; speedup vs baseline: 1.1700x; 1.1700x over previous
//
#include <hip/hip_runtime.h>
#include <hip/hip_fp16.h>
#include <math.h>

// Problem dims
#define Bb 256
#define Nn 196
#define Dd 512
#define Hh 102
#define Kk 64
#define Mm 40

// ws layout (bytes):
//   [0, 25690112)          logits [B][2][N][K] f32
//   [W1H_OFF, +262144)     w1g_hi [2][128][512] bf16 (g-folded, transposed, j-padded)
//   [W1L_OFF, +262144)     w1g_lo
//   [GWB1_OFF, +2048)      gwb1 [2][128][2] f32 (Gw, B1)
//   [W2TH_OFF, +32768)     w2t_hi [2][64 k][128 j] bf16 (transposed, j-padded)
//   [W2TL_OFF, +32768)     w2t_lo
//   [AGG_OFF, +33554432)   aggP [2][B][64][512] fp16    total ~59.8 MB
#define LOGITS_BYTES 25690112
#define W1H_OFF  ((size_t)25690112)
#define W1L_OFF  (W1H_OFF + 262144)
#define GWB1_OFF (W1L_OFF + 262144)
#define W2TH_OFF (GWB1_OFF + 2048)
#define W2TL_OFF (W2TH_OFF + 32768)
#define AGG_OFF  (W2TL_OFF + 32768)

using short8 = __attribute__((ext_vector_type(8))) short;
using f32x4  = __attribute__((ext_vector_type(4))) float;

// T4 barrier: drain LDS queue (writer-side visibility) but leave global
// loads IN FLIGHT across the barrier — no vmcnt(0) drain.
__device__ __forceinline__ void barrier_lgkm_only() {
  asm volatile("s_waitcnt lgkmcnt(0)" ::: "memory");
  __builtin_amdgcn_s_barrier();
  asm volatile("" ::: "memory");
}

__device__ __forceinline__ float dot4(const float4 a, const float4 b) {
  return a.x*b.x + a.y*b.y + a.z*b.z + a.w*b.w;
}
__device__ __forceinline__ float4 ld4s(const float* p) { return *(const float4*)p; }
__device__ __forceinline__ float gelu1(float z) {
  return 0.5f * z * (1.f + erff(z * 0.70710678118f));
}
__device__ __forceinline__ unsigned short bf16hi(float v) {
  return (unsigned short)(__float_as_uint(v) >> 16);
}
__device__ __forceinline__ float hipart(float v) {
  return __uint_as_float(__float_as_uint(v) & 0xffff0000u);
}
__device__ __forceinline__ unsigned short f2h(float v) {
  __half h = __float2half(v);
  return *(unsigned short*)&h;
}
__device__ __forceinline__ float h2f(unsigned short u) {
  __half h = *(__half*)&u;
  return __half2float(h);
}
__device__ __forceinline__ void split8(const float4 va, const float4 vb,
                                       short8& hh, short8& ll) {
  hh[0] = (short)bf16hi(va.x); ll[0] = (short)bf16hi(va.x - hipart(va.x));
  hh[1] = (short)bf16hi(va.y); ll[1] = (short)bf16hi(va.y - hipart(va.y));
  hh[2] = (short)bf16hi(va.z); ll[2] = (short)bf16hi(va.z - hipart(va.z));
  hh[3] = (short)bf16hi(va.w); ll[3] = (short)bf16hi(va.w - hipart(va.w));
  hh[4] = (short)bf16hi(vb.x); ll[4] = (short)bf16hi(vb.x - hipart(vb.x));
  hh[5] = (short)bf16hi(vb.y); ll[5] = (short)bf16hi(vb.y - hipart(vb.y));
  hh[6] = (short)bf16hi(vb.z); ll[6] = (short)bf16hi(vb.z - hipart(vb.z));
  hh[7] = (short)bf16hi(vb.w); ll[7] = (short)bf16hi(vb.w - hipart(vb.w));
}
__device__ __forceinline__ float wave_reduce_sum(float v) {
#pragma unroll
  for (int o = 1; o < 64; o <<= 1) v += __shfl_xor(v, o, 64);
  return v;
}
__device__ __forceinline__ float wave_reduce_max(float v) {
#pragma unroll
  for (int o = 1; o < 64; o <<= 1) v = fmaxf(v, __shfl_xor(v, o, 64));
  return v;
}

// ---------------------------------------------------------------------------
// K0w: grid (2 paths, 9 slices). Slices 0-7: w1g = g(.)w1 transposed, split
// bf16 hi/lo. Slice 0 also Gw/B1. Slice 8: w2 transposed [64 k][128 j] split.
// ---------------------------------------------------------------------------
__global__ __launch_bounds__(512) void k0_wprep(
    const float* __restrict__ g_s, const float* __restrict__ b_s,
    const float* __restrict__ w1_s, const float* __restrict__ b1_s,
    const float* __restrict__ w2_s,
    const float* __restrict__ g_d, const float* __restrict__ b_d,
    const float* __restrict__ w1_d, const float* __restrict__ b1_d,
    const float* __restrict__ w2_d,
    unsigned short* __restrict__ w1h, unsigned short* __restrict__ w1l,
    float* __restrict__ gwb1,
    unsigned short* __restrict__ w2th, unsigned short* __restrict__ w2tl)
{
  const int p = blockIdx.x, slice = blockIdx.y;
  const float* g  = p ? g_d  : g_s;
  const float* bb = p ? b_d  : b_s;
  const float* w1 = p ? w1_d : w1_s;
  const float* b1 = p ? b1_d : b1_s;
  const float* w2 = p ? w2_d : w2_s;
  const int tid = threadIdx.x;

  if (slice < 8) {
    for (int idx = slice * 8192 + tid; idx < slice * 8192 + 8192; idx += 512) {
      const int j = idx & 127, c = idx >> 7;
      const float v = (j < Hh) ? w1[(size_t)c * Hh + j] * g[c] : 0.f;
      w1h[((size_t)(p * 128 + j)) * 512 + c] = bf16hi(v);
      w1l[((size_t)(p * 128 + j)) * 512 + c] = bf16hi(v - hipart(v));
    }
  } else {
    for (int idx = tid; idx < 8192; idx += 512) {
      const int k = idx >> 7, j = idx & 127;
      const float v = (j < Hh) ? w2[(size_t)j * Kk + k] : 0.f;
      w2th[(size_t)(p * 64 + k) * 128 + j] = bf16hi(v);
      w2tl[(size_t)(p * 64 + k) * 128 + j] = bf16hi(v - hipart(v));
    }
  }

  if (slice == 0) {
    __shared__ float red[4][128][2];
    const int j = tid & 127, part = tid >> 7;
    float sg = 0.f, sb = 0.f;
    if (j < Hh) {
      for (int c = part * 128; c < part * 128 + 128; ++c) {
        const float w = w1[(size_t)c * Hh + j];
        sg += g[c] * w;
        sb += bb[c] * w;
      }
    }
    red[part][j][0] = sg;
    red[part][j][1] = sb;
    __syncthreads();
    if (part == 0) {
      const float G  = red[0][j][0] + red[1][j][0] + red[2][j][0] + red[3][j][0];
      const float Bv = red[0][j][1] + red[1][j][1] + red[2][j][1] + red[3][j][1];
      gwb1[(p * 128 + j) * 2]     = G;
      gwb1[(p * 128 + j) * 2 + 1] = (j < Hh) ? (Bv + b1[j]) : 0.f;
    }
  }
}

// ---------------------------------------------------------------------------
// K1: per 112-token tile of one (b, path). r14/r16 config (best measured):
// double-buffered split-bf16 MFMA K-loop, T4 barriers, depth-2 x prefetch,
// wave-per-j-tile map. LN folded into epilogue. Phase-2: split-bf16 MFMA
// against LDS-resident h (w2t frags direct from global, L2-hot).
// ---------------------------------------------------------------------------
__global__ __launch_bounds__(512) void k1_logits(
    const float* __restrict__ x_s, const float* __restrict__ x_d,
    const unsigned short* __restrict__ w1h, const unsigned short* __restrict__ w1l,
    const float* __restrict__ gwb1,
    const unsigned short* __restrict__ w2th, const unsigned short* __restrict__ w2tl,
    const float* __restrict__ b2_s, const float* __restrict__ b2_d,
    float* __restrict__ logits)
{
  __shared__ __align__(16) char smem1[40320];
  unsigned short* xbuf = (unsigned short*)smem1;
  unsigned short* hs_h = (unsigned short*)smem1;            // [112][72]
  unsigned short* hs_l = (unsigned short*)(smem1 + 16128);  // [112][72]
  float* part = (float*)(smem1 + 35840);
  float* st   = (float*)(smem1 + 39424);

  const int tid = threadIdx.x;
  const int ntile = blockIdx.x, p = blockIdx.y, b = blockIdx.z;
  const int nbase = ntile * 112;
  const float* x  = p ? x_d : x_s;
  const float* b2 = p ? b2_d : b2_s;

  const int lane = tid & 63, wv = tid >> 6;
  const int lr = lane & 15, lg = lane >> 4;
  const int jb = wv * 16;
  const unsigned short* wph = w1h + ((size_t)(p * 128 + jb + lr)) * 512 + lg * 8;
  const unsigned short* wpl = w1l + ((size_t)(p * 128 + jb + lr)) * 512 + lg * 8;

  const int t = tid >> 2, q = tid & 3;
  const bool stg = (tid < 448);
  const int n = nbase + t;
  const bool valid = stg && (n < Nn);
  const float* xrow = x + ((size_t)(b * Nn + (valid ? n : 0))) * Dd + q * 8;

  float psum = 0.f, psq = 0.f;
  f32x4 acc0 = {0,0,0,0}, acc1 = acc0, acc2 = acc0, acc3 = acc0;
  f32x4 acc4 = acc0, acc5 = acc0, acc6 = acc0;

  short8 bh_c = *(const short8*)(wph);
  short8 bl_c = *(const short8*)(wpl);

  // prologue: chunk 0 staged to buf 0; pend = loads for chunk 1
  {
    float4 va = {0,0,0,0}, vb = va;
    if (valid) { va = ld4s(xrow); vb = ld4s(xrow + 4); }
    if (stg) {
      psum += va.x + va.y + va.z + va.w + vb.x + vb.y + vb.z + vb.w;
      psq  += dot4(va, va) + dot4(vb, vb);
      short8 hh, ll;
      split8(va, vb, hh, ll);
      *(short8*)(xbuf + t * 40 + q * 8) = hh;
      *(short8*)(xbuf + 4480 + t * 40 + q * 8) = ll;
    }
  }
  float4 pva = {0,0,0,0}, pvb = pva;
  if (valid) { pva = ld4s(xrow + 32); pvb = ld4s(xrow + 36); }
  barrier_lgkm_only();

#pragma unroll 1
  for (int ch = 0; ch < 16; ++ch) {
    const int buf = ch & 1;
    const unsigned short* xh = xbuf + buf * 8960;
    const unsigned short* xl = xh + 4480;

    float4 nva = {0,0,0,0}, nvb = nva;
    if (ch < 14 && valid) {
      const int co = (ch + 2) * 32;
      nva = ld4s(xrow + co);
      nvb = ld4s(xrow + co + 4);
    }
    short8 bh_n = bh_c, bl_n = bl_c;
    if (ch < 15) {
      const int co = (ch + 1) * 32;
      bh_n = *(const short8*)(wph + co);
      bl_n = *(const short8*)(wpl + co);
    }

#define MSTEP(A, M) { \
    const short8 ah = *(const short8*)(xh + ((M) * 16 + lr) * 40 + lg * 8); \
    const short8 al = *(const short8*)(xl + ((M) * 16 + lr) * 40 + lg * 8); \
    (A) = __builtin_amdgcn_mfma_f32_16x16x32_bf16(ah, bh_c, (A), 0, 0, 0); \
    (A) = __builtin_amdgcn_mfma_f32_16x16x32_bf16(ah, bl_c, (A), 0, 0, 0); \
    (A) = __builtin_amdgcn_mfma_f32_16x16x32_bf16(al, bh_c, (A), 0, 0, 0); }
    MSTEP(acc0, 0) MSTEP(acc1, 1) MSTEP(acc2, 2) MSTEP(acc3, 3)
    MSTEP(acc4, 4) MSTEP(acc5, 5) MSTEP(acc6, 6)
#undef MSTEP

    if (ch < 15 && stg) {
      psum += pva.x + pva.y + pva.z + pva.w + pvb.x + pvb.y + pvb.z + pvb.w;
      psq  += dot4(pva, pva) + dot4(pvb, pvb);
      short8 hh, ll;
      split8(pva, pvb, hh, ll);
      unsigned short* xw = xbuf + (buf ^ 1) * 8960;
      *(short8*)(xw + t * 40 + q * 8) = hh;
      *(short8*)(xw + 4480 + t * 40 + q * 8) = ll;
    }
    pva = nva; pvb = nvb;
    bh_c = bh_n; bl_c = bl_n;
    barrier_lgkm_only();
  }

  if (stg) {
    part[t * 8 + q * 2]     = psum;
    part[t * 8 + q * 2 + 1] = psq;
  }
  __syncthreads();
  if (tid < 112) {
    const float s  = part[tid * 8] + part[tid * 8 + 2] + part[tid * 8 + 4] + part[tid * 8 + 6];
    const float ss = part[tid * 8 + 1] + part[tid * 8 + 3] + part[tid * 8 + 5] + part[tid * 8 + 7];
    const float mu  = s * (1.f / 512.f);
    const float var = fmaxf(ss * (1.f / 512.f) - mu * mu, 0.f);
    st[2 * tid]     = mu;
    st[2 * tid + 1] = rsqrtf(var + 1e-5f);
  }
  __syncthreads();

  const int colw = jb + lr;
  const float Gw = gwb1[(p * 128 + colw) * 2];
  const float B1 = gwb1[(p * 128 + colw) * 2 + 1];
  const int hwv  = wv >> 2;
  const int jloc = colw & 63;

#define HW1(A, M) { \
    _Pragma("unroll") \
    for (int rr = 0; rr < 4; ++rr) { \
      const int row = (M) * 16 + lg * 4 + rr; \
      const float mu = st[2 * row], rs = st[2 * row + 1]; \
      const float hv = gelu1(rs * (A)[rr] - mu * rs * Gw + B1); \
      hs_h[row * 72 + jloc] = bf16hi(hv); \
      hs_l[row * 72 + jloc] = bf16hi(hv - hipart(hv)); \
    } }
#define HWALL { HW1(acc0,0) HW1(acc1,1) HW1(acc2,2) HW1(acc3,3) \
                HW1(acc4,4) HW1(acc5,5) HW1(acc6,6) }

  f32x4 C0 = {0,0,0,0}, C1 = C0, C2 = C0, C3 = C0;
  const unsigned short* w2hb = w2th + (size_t)p * 8192 + lr * 128 + lg * 8;
  const unsigned short* w2lb = w2tl + (size_t)p * 8192 + lr * 128 + lg * 8;
  const int arow = (wv * 16 + lr) * 72 + lg * 8;

#define P2STEP(JG) { \
    const short8 Ah = *(const short8*)(hs_h + arow + ((JG) & 63)); \
    const short8 Al = *(const short8*)(hs_l + arow + ((JG) & 63)); \
    const short8 Bh0 = *(const short8*)(w2hb + (JG)); \
    const short8 Bl0 = *(const short8*)(w2lb + (JG)); \
    const short8 Bh1 = *(const short8*)(w2hb + 16 * 128 + (JG)); \
    const short8 Bl1 = *(const short8*)(w2lb + 16 * 128 + (JG)); \
    const short8 Bh2 = *(const short8*)(w2hb + 32 * 128 + (JG)); \
    const short8 Bl2 = *(const short8*)(w2lb + 32 * 128 + (JG)); \
    const short8 Bh3 = *(const short8*)(w2hb + 48 * 128 + (JG)); \
    const short8 Bl3 = *(const short8*)(w2lb + 48 * 128 + (JG)); \
    C0 = __builtin_amdgcn_mfma_f32_16x16x32_bf16(Ah, Bh0, C0, 0, 0, 0); \
    C0 = __builtin_amdgcn_mfma_f32_16x16x32_bf16(Ah, Bl0, C0, 0, 0, 0); \
    C0 = __builtin_amdgcn_mfma_f32_16x16x32_bf16(Al, Bh0, C0, 0, 0, 0); \
    C1 = __builtin_amdgcn_mfma_f32_16x16x32_bf16(Ah, Bh1, C1, 0, 0, 0); \
    C1 = __builtin_amdgcn_mfma_f32_16x16x32_bf16(Ah, Bl1, C1, 0, 0, 0); \
    C1 = __builtin_amdgcn_mfma_f32_16x16x32_bf16(Al, Bh1, C1, 0, 0, 0); \
    C2 = __builtin_amdgcn_mfma_f32_16x16x32_bf16(Ah, Bh2, C2, 0, 0, 0); \
    C2 = __builtin_amdgcn_mfma_f32_16x16x32_bf16(Ah, Bl2, C2, 0, 0, 0); \
    C2 = __builtin_amdgcn_mfma_f32_16x16x32_bf16(Al, Bh2, C2, 0, 0, 0); \
    C3 = __builtin_amdgcn_mfma_f32_16x16x32_bf16(Ah, Bh3, C3, 0, 0, 0); \
    C3 = __builtin_amdgcn_mfma_f32_16x16x32_bf16(Ah, Bl3, C3, 0, 0, 0); \
    C3 = __builtin_amdgcn_mfma_f32_16x16x32_bf16(Al, Bh3, C3, 0, 0, 0); }

  if (hwv == 0) { HWALL }
  __syncthreads();
  if (wv < 7) { P2STEP(0) P2STEP(32) }
  __syncthreads();
  if (hwv == 1) { HWALL }
  __syncthreads();
  if (wv < 7) { P2STEP(64) P2STEP(96) }
#undef P2STEP
#undef HWALL
#undef HW1

  if (wv < 7) {
    const float bb0 = b2[lr], bb1 = b2[16 + lr];
    const float bb2 = b2[32 + lr], bb3 = b2[48 + lr];
#pragma unroll
    for (int rr = 0; rr < 4; ++rr) {
      const int tok = wv * 16 + lg * 4 + rr;
      const int nn = nbase + tok;
      if (nn < Nn) {
        float* lgp = logits + ((size_t)(b * 2 + p) * Nn + nn) * Kk;
        lgp[lr]      = C0[rr] + bb0;
        lgp[16 + lr] = C1[rr] + bb1;
        lgp[32 + lr] = C2[rr] + bb2;
        lgp[48 + lr] = C3[rr] + bb3;
      }
    }
  }
}

// ---------------------------------------------------------------------------
// K2 v4h: ONE block per (p, b). Softmax -> e split-bf16 swizzled -> A-frags in
// regs. Packed b64 staging writes; swizzle (row&31)<<3. aggP out as FP16.
// ---------------------------------------------------------------------------
__global__ __launch_bounds__(512) void k2_softmax_agg(
    const float* __restrict__ x_s, const float* __restrict__ x_d,
    const float* __restrict__ logits, const float* __restrict__ scale,
    unsigned short* __restrict__ aggP)
{
  __shared__ __align__(16) unsigned char smem2[68224];
  unsigned short* eh = (unsigned short*)smem2;
  unsigned short* el = (unsigned short*)(smem2 + 32768);
  float* rsk  = (float*)(smem2 + 65536);
  float* redf = (float*)(smem2 + 65792);
  float* mxk  = (float*)(smem2 + 67968);

  const int tid = threadIdx.x;
  const int p = blockIdx.x, b = blockIdx.y;
  const float sc = scale[0];
  const float* xb = (p ? x_d : x_s) + (size_t)b * Nn * Dd;

  const int kloc = tid & 63, sprt = tid >> 6;
  const float* lgp = logits + ((size_t)(b * 2 + p) * Nn) * Kk + kloc;
  const int eswz = (kloc & 31) << 3;
  float mx = -1e30f;
  for (int nn = sprt; nn < Nn; nn += 8) mx = fmaxf(mx, lgp[nn * 64] * sc);
  redf[sprt * 68 + kloc] = mx;
  __syncthreads();
  if (tid < 64) {
    float m = redf[tid];
#pragma unroll
    for (int gg = 1; gg < 8; ++gg) m = fmaxf(m, redf[gg * 68 + tid]);
    mxk[tid] = m;
  }
  __syncthreads();
  const float mk = mxk[kloc];
  float ssum = 0.f;
  for (int nn = sprt; nn < Nn; nn += 8) {
    const float e = expf(lgp[nn * 64] * sc - mk);
    const int ph = kloc * 256 + (nn ^ eswz);
    eh[ph] = bf16hi(e);
    el[ph] = bf16hi(e - hipart(e));
    ssum += e;
  }
  for (int nn = Nn + sprt; nn < 224; nn += 8) {
    const int ph = kloc * 256 + (nn ^ eswz);
    eh[ph] = 0; el[ph] = 0;
  }
  redf[sprt * 68 + kloc] = ssum;
  __syncthreads();
  if (tid < 64) {
    float s = 0.f;
#pragma unroll
    for (int gg = 0; gg < 8; ++gg) s += redf[gg * 68 + tid];
    rsk[tid] = 1.f / s;
  }
  __syncthreads();

  const int lane = tid & 63, wv = tid >> 6;
  const int lr = lane & 15, lg = lane >> 4;
  const int kt = wv & 3, ct = wv >> 2;
  const int arow = kt * 16 + lr;
  const int aswz = (arow & 31) << 3;
  const unsigned short* ebh = eh + arow * 256;
  const unsigned short* ebl = el + arow * 256;
  short8 Ah0, Ah1, Ah2, Ah3, Ah4, Ah5, Ah6;
  short8 Al0, Al1, Al2, Al3, Al4, Al5, Al6;
#define LDA(I) { const int off = ((I) * 32 + lg * 8) ^ aswz; \
  Ah##I = *(const short8*)(ebh + off); \
  Al##I = *(const short8*)(ebl + off); }
  LDA(0) LDA(1) LDA(2) LDA(3) LDA(4) LDA(5) LDA(6)
#undef LDA
  const int kbase = kt * 16 + lg * 4;
  const float r0 = rsk[kbase], r1 = rsk[kbase + 1];
  const float r2 = rsk[kbase + 2], r3 = rsk[kbase + 3];
  barrier_lgkm_only();

  const int brow = ct * 16 + lr;
  const int bswz = (brow & 31) << 3;
  const size_t agk = (size_t)((p * Bb + b) * Kk + kbase) * Dd;

#define K2STAGE(CHN, BUF) { \
    const int c0s = (CHN) * 32; \
    unsigned short* th = (unsigned short*)(smem2 + (BUF) * 32768); \
    unsigned short* tl = (unsigned short*)(smem2 + (BUF) * 32768 + 16384); \
    _Pragma("unroll") \
    for (int it = 0; it < 4; ++it) { \
      const int idx = it * 512 + tid; \
      const int cl = idx & 31, ngr = idx >> 5; \
      if (ngr < 56) { \
        const int n0 = ngr * 4; \
        const float* xpp = xb + (size_t)n0 * Dd + c0s + cl; \
        const float v0 = (n0     < Nn) ? xpp[0]      : 0.f; \
        const float v1 = (n0 + 1 < Nn) ? xpp[Dd]     : 0.f; \
        const float v2 = (n0 + 2 < Nn) ? xpp[2 * Dd] : 0.f; \
        const float v3 = (n0 + 3 < Nn) ? xpp[3 * Dd] : 0.f; \
        ushort4 hh4, ll4; \
        hh4.x = bf16hi(v0); ll4.x = bf16hi(v0 - hipart(v0)); \
        hh4.y = bf16hi(v1); ll4.y = bf16hi(v1 - hipart(v1)); \
        hh4.z = bf16hi(v2); ll4.z = bf16hi(v2 - hipart(v2)); \
        hh4.w = bf16hi(v3); ll4.w = bf16hi(v3 - hipart(v3)); \
        const int ph = cl * 256 + (n0 ^ ((cl & 31) << 3)); \
        *(ushort4*)(th + ph) = hh4; \
        *(ushort4*)(tl + ph) = ll4; \
      } \
    } }

  K2STAGE(0, 0)
  barrier_lgkm_only();

#pragma unroll 1
  for (int chn = 0; chn < 16; ++chn) {
    const int buf = chn & 1;
    if (chn < 15) { K2STAGE(chn + 1, buf ^ 1) }

    const unsigned short* bhb = (const unsigned short*)(smem2 + buf * 32768) + brow * 256;
    const unsigned short* blb = (const unsigned short*)(smem2 + buf * 32768 + 16384) + brow * 256;
    f32x4 acc = {0.f, 0.f, 0.f, 0.f};
#define K2KS(I) { \
    const int off = ((I) * 32 + lg * 8) ^ bswz; \
    const short8 Bh = *(const short8*)(bhb + off); \
    const short8 Bl = *(const short8*)(blb + off); \
    acc = __builtin_amdgcn_mfma_f32_16x16x32_bf16(Ah##I, Bh, acc, 0, 0, 0); \
    acc = __builtin_amdgcn_mfma_f32_16x16x32_bf16(Ah##I, Bl, acc, 0, 0, 0); \
    acc = __builtin_amdgcn_mfma_f32_16x16x32_bf16(Al##I, Bh, acc, 0, 0, 0); }
    K2KS(0) K2KS(1) K2KS(2) K2KS(3) K2KS(4) K2KS(5) K2KS(6)
#undef K2KS

    const int cc = chn * 32 + ct * 16 + lr;
    aggP[agk              + cc] = f2h(acc[0] * r0);
    aggP[agk +     (size_t)Dd + cc] = f2h(acc[1] * r1);
    aggP[agk + 2 * (size_t)Dd + cc] = f2h(acc[2] * r2);
    aggP[agk + 3 * (size_t)Dd + cc] = f2h(acc[3] * r3);
    barrier_lgkm_only();
  }
#undef K2STAGE
}

// ---------------------------------------------------------------------------
// K4: per b, 512 threads: lane owns k; swizzled vt LDS; register dots.
// aggP is fp16 (converted to f32 at staging).
// ---------------------------------------------------------------------------
__global__ __launch_bounds__(512) void k4_final(
    const float* __restrict__ words, const unsigned short* __restrict__ aggP,
    float* __restrict__ outp)
{
  __shared__ __align__(16) unsigned char vls[64 * 512];
  __shared__ float rowm[40];
  __shared__ float colp[8][72];
  const int tid = threadIdx.x, b = blockIdx.x;
  const int w = tid >> 6, lane = tid & 63;
  const unsigned short* a0 = aggP + (size_t)b * (Kk * Dd);
  const unsigned short* a1 = aggP + ((size_t)(Bb + b)) * (Kk * Dd);
  const float* wrd = words + (size_t)b * Mm * Dd;
  const int m0 = w * 5;

  float rnt0, rnt1, rnt2, rnt3, rnt4;
#define TNORM(R, I) { \
    const float* tr = wrd + (size_t)(m0 + (I)) * Dd + lane * 8; \
    float4 ta = ld4s(tr), tb = ld4s(tr + 4); \
    float ss = wave_reduce_sum(dot4(ta, ta) + dot4(tb, tb)); \
    R = 1.f / fmaxf(sqrtf(ss), 1e-8f); }
  TNORM(rnt0, 0) TNORM(rnt1, 1) TNORM(rnt2, 2) TNORM(rnt3, 3) TNORM(rnt4, 4)
#undef TNORM

  float acc0 = 0.f, acc1 = 0.f, acc2 = 0.f, acc3 = 0.f, acc4 = 0.f, vsq = 0.f;

#pragma unroll 1
  for (int chn = 0; chn < 4; ++chn) {
    const int c0 = chn * 128;
    __syncthreads();
#pragma unroll
    for (int s = 0; s < 2; ++s) {
      const int idx = tid + s * 512;
      const int k = idx >> 4, g2 = idx & 15;
      const unsigned short* ph0 = a0 + (size_t)k * Dd + c0 + g2 * 8;
      const unsigned short* ph1 = a1 + (size_t)k * Dd + c0 + g2 * 8;
      const ushort4 u0a = *(const ushort4*)(ph0);
      const ushort4 u0b = *(const ushort4*)(ph0 + 4);
      const ushort4 u1a = *(const ushort4*)(ph1);
      const ushort4 u1b = *(const ushort4*)(ph1 + 4);
      float4 sa = {h2f(u0a.x) + h2f(u1a.x), h2f(u0a.y) + h2f(u1a.y),
                   h2f(u0a.z) + h2f(u1a.z), h2f(u0a.w) + h2f(u1a.w)};
      float4 sb = {h2f(u0b.x) + h2f(u1b.x), h2f(u0b.y) + h2f(u1b.y),
                   h2f(u0b.z) + h2f(u1b.z), h2f(u0b.w) + h2f(u1b.w)};
      const int gc0 = g2 * 2, gc1 = gc0 + 1;
      *(float4*)(vls + k * 512 + ((gc0 ^ (k & 31)) << 4)) = sa;
      *(float4*)(vls + k * 512 + ((gc1 ^ (k & 31)) << 4)) = sb;
    }
    __syncthreads();
#pragma unroll 2
    for (int cc = 0; cc < 32; ++cc) {
      const float4 vv = *(const float4*)(vls + lane * 512 + ((cc ^ (lane & 31)) << 4));
      const float* tp = wrd + c0 + cc * 4;
      const float4 t0 = ld4s(tp + (size_t)(m0    ) * Dd);
      const float4 t1 = ld4s(tp + (size_t)(m0 + 1) * Dd);
      const float4 t2 = ld4s(tp + (size_t)(m0 + 2) * Dd);
      const float4 t3 = ld4s(tp + (size_t)(m0 + 3) * Dd);
      const float4 t4 = ld4s(tp + (size_t)(m0 + 4) * Dd);
      acc0 += dot4(t0, vv); acc1 += dot4(t1, vv); acc2 += dot4(t2, vv);
      acc3 += dot4(t3, vv); acc4 += dot4(t4, vv);
      vsq  += dot4(vv, vv);
    }
  }

  const float rnv = 1.f / fmaxf(sqrtf(vsq), 1e-8f);
  float cmax = -1e30f;
#define DOM(ACC, RNT, I) { \
    float s = (ACC) * (RNT) * rnv; \
    s = (s >= 0.f) ? s : 0.1f * s; \
    cmax = fmaxf(cmax, s); \
    float rm = wave_reduce_max(s); \
    if (lane == 0) rowm[m0 + (I)] = rm; }
  DOM(acc0, rnt0, 0) DOM(acc1, rnt1, 1) DOM(acc2, rnt2, 2)
  DOM(acc3, rnt3, 3) DOM(acc4, rnt4, 4)
#undef DOM
  colp[w][lane] = cmax;
  __syncthreads();
  if (w == 0) {
    float cm = colp[0][lane];
#pragma unroll
    for (int ww = 1; ww < 8; ++ww) cm = fmaxf(cm, colp[ww][lane]);
    const float csum = wave_reduce_sum(cm);
    const float rv = (lane < 40) ? rowm[lane] : 0.f;
    const float rsum = wave_reduce_sum(rv);
    if (lane == 0) outp[b] = rsum * (1.f / 40.f) + csum * (1.f / 64.f);
  }
}

extern "C" void kernel_launch(void* const* d_in, const int* in_sizes, int n_in,
                              void* d_out, int out_size, void* d_ws, size_t ws_size,
                              hipStream_t stream)
{
  const float* x_s   = (const float*)d_in[0];
  const float* x_d   = (const float*)d_in[1];
  const float* words = (const float*)d_in[2];
  const float* g_s   = (const float*)d_in[3];
  const float* b_s   = (const float*)d_in[4];
  const float* w1_s  = (const float*)d_in[5];
  const float* b1_s  = (const float*)d_in[6];
  const float* w2_s  = (const float*)d_in[7];
  const float* b2_s  = (const float*)d_in[8];
  const float* g_d   = (const float*)d_in[9];
  const float* b_d   = (const float*)d_in[10];
  const float* w1_d  = (const float*)d_in[11];
  const float* b1_d  = (const float*)d_in[12];
  const float* w2_d  = (const float*)d_in[13];
  const float* b2_d  = (const float*)d_in[14];
  const float* scale = (const float*)d_in[15];
  (void)in_sizes; (void)n_in; (void)out_size; (void)ws_size;

  char* ws = (char*)d_ws;
  float* logits        = (float*)ws;
  unsigned short* w1h  = (unsigned short*)(ws + W1H_OFF);
  unsigned short* w1l  = (unsigned short*)(ws + W1L_OFF);
  float* gwb1          = (float*)(ws + GWB1_OFF);
  unsigned short* w2th = (unsigned short*)(ws + W2TH_OFF);
  unsigned short* w2tl = (unsigned short*)(ws + W2TL_OFF);
  unsigned short* aggP = (unsigned short*)(ws + AGG_OFF);

  hipLaunchKernelGGL(k0_wprep, dim3(2, 9), dim3(512), 0, stream,
                     g_s, b_s, w1_s, b1_s, w2_s, g_d, b_d, w1_d, b1_d, w2_d,
                     w1h, w1l, gwb1, w2th, w2tl);
  hipLaunchKernelGGL(k1_logits, dim3(2, 2, 256), dim3(512), 0, stream,
                     x_s, x_d, w1h, w1l, gwb1, w2th, w2tl,
                     b2_s, b2_d, logits);
  hipLaunchKernelGGL(k2_softmax_agg, dim3(2, Bb), dim3(512), 0, stream,
                     x_s, x_d, logits, scale, aggP);
  hipLaunchKernelGGL(k4_final, dim3(256), dim3(512), 0, stream,
                     words, aggP, (float*)d_out);
}